// Round 7
// baseline (527.581 us; speedup 1.0000x reference)
//
#include <hip/hip_runtime.h>
#include <hip/hip_bf16.h>
#include <stdint.h>

#define DMODEL 1024
#define NEXP 32
#define ESZ 256
#define NTOK 8192
#define NH 4

typedef __hip_bfloat16 bf16;
typedef short bf16x8 __attribute__((ext_vector_type(8)));
typedef float f32x4 __attribute__((ext_vector_type(4)));

__device__ __forceinline__ void pack8(const float4& a, const float4& b, bf16* t) {
    t[0] = __float2bfloat16(a.x); t[1] = __float2bfloat16(a.y);
    t[2] = __float2bfloat16(a.z); t[3] = __float2bfloat16(a.w);
    t[4] = __float2bfloat16(b.x); t[5] = __float2bfloat16(b.y);
    t[6] = __float2bfloat16(b.z); t[7] = __float2bfloat16(b.w);
}

// XOR swizzle for [rows][64] bf16 LDS tiles accessed in 16B blocks.
// Row stride 64 elems = 32 dwords (== 0 mod 32 -> all rows same bank w/o swizzle);
// XOR of 16B-block index with (row&7) spreads rows across bank groups: measured-free 2-way.
__device__ __forceinline__ int sw(int r, int c) {
    return (r << 6) + ((((c >> 3) ^ r) & 7) << 3) + (c & 7);
}

// ---------------- selection (pure f32): logits -> top-4 -> gates (NO atomics) ----------------
__global__ void sel_kernel(const float* __restrict__ x, const float* __restrict__ esel,
                           int* __restrict__ eidx, float* __restrict__ egate) {
    int lane = threadIdx.x & 63;
    int wid = threadIdx.x >> 6;
    int t = blockIdx.x * 4 + wid;

    const float* xp = x + (size_t)t * DMODEL + lane * 16;
    float xv[16];
    *(float4*)&xv[0]  = *(const float4*)(xp);
    *(float4*)&xv[4]  = *(const float4*)(xp + 4);
    *(float4*)&xv[8]  = *(const float4*)(xp + 8);
    *(float4*)&xv[12] = *(const float4*)(xp + 12);

    __shared__ float sc[4][NEXP];
    for (int e = 0; e < NEXP; ++e) {
        const float* sp = esel + (size_t)e * DMODEL + lane * 16;
        float4 p0 = *(const float4*)(sp);
        float4 p1 = *(const float4*)(sp + 4);
        float4 p2 = *(const float4*)(sp + 8);
        float4 p3 = *(const float4*)(sp + 12);
        float s = xv[0]*p0.x + xv[1]*p0.y + xv[2]*p0.z + xv[3]*p0.w
                + xv[4]*p1.x + xv[5]*p1.y + xv[6]*p1.z + xv[7]*p1.w
                + xv[8]*p2.x + xv[9]*p2.y + xv[10]*p2.z + xv[11]*p2.w
                + xv[12]*p3.x + xv[13]*p3.y + xv[14]*p3.z + xv[15]*p3.w;
        #pragma unroll
        for (int o = 32; o > 0; o >>= 1) s += __shfl_xor(s, o, 64);
        if (lane == 0) sc[wid][e] = s;
    }

    if (lane == 0) {
        // strict > scan: lowest index wins ties (matches lax.top_k; sigmoid is monotone)
        for (int j = 0; j < NH; ++j) {
            float m = -1e30f; int mi = 0;
            for (int e = 0; e < NEXP; ++e) {
                float v = sc[wid][e];
                if (v > m) { m = v; mi = e; }
            }
            sc[wid][mi] = -1e30f;
            float g = 1.f / (1.f + expf(-m));
            eidx[t * NH + j] = mi;
            egate[t * NH + j] = g;
        }
    }
}

// ---------------- per-expert histogram (contention-free) ----------------
__global__ void hist_kernel(const int* __restrict__ eidx, int* __restrict__ counts,
                            int* __restrict__ counts_q) {
    int e = blockIdx.x;
    int w = threadIdx.x >> 6;
    int lane = threadIdx.x & 63;
    const int* p = eidx + w * 8192;
    int cnt = 0;
    for (int it = 0; it < 128; ++it)
        cnt += (p[it * 64 + lane] == e);
    #pragma unroll
    for (int o = 32; o > 0; o >>= 1) cnt += __shfl_xor(cnt, o, 64);
    __shared__ int s_q[4];
    if (lane == 0) s_q[w] = cnt;
    __syncthreads();
    if (threadIdx.x == 0) {
        counts[e] = s_q[0] + s_q[1] + s_q[2] + s_q[3];
        counts_q[e * 4 + 0] = s_q[0];
        counts_q[e * 4 + 1] = s_q[1];
        counts_q[e * 4 + 2] = s_q[2];
        counts_q[e * 4 + 3] = s_q[3];
    }
}

// ---------------- tiny exclusive scan over 32 counts ----------------
__global__ void scan_kernel(const int* __restrict__ counts, int* __restrict__ offsets) {
    if (threadIdx.x == 0) {
        int s = 0;
        for (int e = 0; e < NEXP; ++e) { offsets[e] = s; s += counts[e]; }
    }
}

// ---------------- deterministic ballot compaction (NO atomics) ----------------
__global__ void compact_kernel(const int* __restrict__ eidx, const float* __restrict__ egate,
                               const int* __restrict__ offsets, const int* __restrict__ counts_q,
                               int* __restrict__ btok, float* __restrict__ bgate) {
    int e = blockIdx.x;
    int q = blockIdx.y;
    int lane = threadIdx.x;
    int base = offsets[e];
    #pragma unroll
    for (int k = 0; k < 4; ++k) if (k < q) base += counts_q[e * 4 + k];
    const int* p = eidx + q * 8192;
    const float* g = egate + q * 8192;
    int v = p[lane];
    for (int it = 0; it < 128; ++it) {
        int v_next = (it < 127) ? p[(it + 1) * 64 + lane] : 0;
        unsigned long long m = __ballot(v == e);
        if (v == e) {
            int i = it * 64 + lane;
            int pos = base + __popcll(m & ((1ull << lane) - 1ull));
            btok[pos] = (q * 8192 + i) >> 2;
            bgate[pos] = g[i];
        }
        base += __popcll(m);
        v = v_next;
    }
}

// ---------------- per-expert transpose+convert: f32 in[e][R][C] -> bf16 out[e][C][R] ----------------
__global__ void transpose_conv_kernel(const float* __restrict__ in, bf16* __restrict__ out,
                                      int R, int C) {
    __shared__ bf16 tile[64][72];
    int e = blockIdx.z, tr = blockIdx.y, tc = blockIdx.x;
    const float* src = in + ((size_t)e * R + tr * 64) * C + tc * 64;
    #pragma unroll
    for (int i = 0; i < 2; ++i) {
        int c = threadIdx.x + 256 * i;
        int r = c >> 3, c8 = c & 7;
        float4 p0 = *(const float4*)(src + (size_t)r * C + c8 * 8);
        float4 p1 = *(const float4*)(src + (size_t)r * C + c8 * 8 + 4);
        bf16 t8[8];
        pack8(p0, p1, t8);
        *(uint4*)&tile[r][c8 * 8] = *(uint4*)t8;
    }
    __syncthreads();
    bf16* dst = out + ((size_t)e * C + tc * 64) * R + tr * 64;
    #pragma unroll
    for (int i = 0; i < 2; ++i) {
        int c = threadIdx.x + 256 * i;
        int oc = c >> 3, c8 = c & 7;
        bf16 tmp[8];
        #pragma unroll
        for (int j = 0; j < 8; ++j) tmp[j] = tile[c8 * 8 + j][oc];
        *(uint4*)(dst + (size_t)oc * R + c8 * 8) = *(uint4*)tmp;
    }
}

// ---------------- kernel A: H[pos][256] = relu(Xg @ K_e) * gate  (bf16) ----------------
// 512 threads (8 waves), tile = 128 tokens x 256 h, K=1024 in 16 steps of 64.
__global__ __launch_bounds__(512) void expert_xk_kernel(
    const float* __restrict__ x, const bf16* __restrict__ keysT,
    const int* __restrict__ counts, const int* __restrict__ offsets,
    const int* __restrict__ btok, const float* __restrict__ bgate,
    bf16* __restrict__ Hout) {
    int e = blockIdx.y;
    int n = counts[e];
    int tile = blockIdx.x;
    if (tile * 128 >= n) return;
    int off = offsets[e];
    int tid = threadIdx.x, lane = tid & 63, w = tid >> 6;
    int lr = lane & 15, lg = lane >> 4;

    __shared__ __align__(16) bf16 Xg[128 * 64];   // 16 KB, swizzled
    __shared__ __align__(16) bf16 KT[256 * 64];   // 32 KB, swizzled
    __shared__ int s_tok[128];
    __shared__ float s_gate[128];

    if (tid < 128) {
        int idxr = tile * 128 + tid;
        bool valid = idxr < n;
        int tok = valid ? btok[off + idxr] : 0;
        s_tok[tid] = tok & (NTOK - 1);
        float g = valid ? bgate[off + idxr] : 0.f;
        s_gate[tid] = (g == g) ? g : 0.f;
    }
    __syncthreads();

    f32x4 acc[16] = {};   // wave w: rows [16w,16w+16) x cols [0,256)
    const bf16* kbase = keysT + (size_t)e * (ESZ * DMODEL);
    int r0 = tid >> 3;          // 0..63
    int c8 = (tid & 7) * 8;
    const float* xr0 = x + (size_t)s_tok[r0] * DMODEL;
    const float* xr1 = x + (size_t)s_tok[r0 + 64] * DMODEL;

    for (int kb = 0; kb < 16; ++kb) {
        int kcol = kb * 64 + c8;
        {   // stage Xg rows r0, r0+64 with inline f32->bf16
            float4 a0 = *(const float4*)(xr0 + kcol);
            float4 a1 = *(const float4*)(xr0 + kcol + 4);
            bf16 t8[8]; pack8(a0, a1, t8);
            *(uint4*)&Xg[sw(r0, c8)] = *(uint4*)t8;
            float4 b0 = *(const float4*)(xr1 + kcol);
            float4 b1 = *(const float4*)(xr1 + kcol + 4);
            pack8(b0, b1, t8);
            *(uint4*)&Xg[sw(r0 + 64, c8)] = *(uint4*)t8;
        }
        #pragma unroll
        for (int i = 0; i < 4; ++i) {   // stage KT [256][64]
            int h = r0 + 64 * i;
            *(uint4*)&KT[sw(h, c8)] = *(const uint4*)(kbase + (size_t)h * DMODEL + kcol);
        }
        __syncthreads();
        #pragma unroll
        for (int ks = 0; ks < 2; ++ks) {
            bf16x8 a = *(bf16x8*)&Xg[sw(w * 16 + lr, ks * 32 + lg * 8)];
            #pragma unroll
            for (int ct = 0; ct < 16; ++ct) {
                bf16x8 b = *(bf16x8*)&KT[sw(ct * 16 + lr, ks * 32 + lg * 8)];
                acc[ct] = __builtin_amdgcn_mfma_f32_16x16x32_bf16(a, b, acc[ct], 0, 0, 0);
            }
        }
        __syncthreads();
    }

    // epilogue: relu * gate -> H (bucket-row-major)
    int rbase = w * 16 + lg * 4;
    int tbase = tile * 128;
    #pragma unroll
    for (int r = 0; r < 4; ++r) {
        int row = rbase + r;
        if (tbase + row < n) {
            float g = s_gate[row];
            bf16* hp = Hout + (size_t)(off + tbase + row) * ESZ;
            #pragma unroll
            for (int ct = 0; ct < 16; ++ct)
                hp[ct * 16 + lr] = __float2bfloat16(fmaxf(acc[ct][r], 0.f) * g);
        }
    }
}

// ---------------- kernel B: yacc[tok] += H @ V_e  (v-chunked, atomic f32) ----------------
// 512 threads (8 waves), tile = 128 tokens x 256 v, K=256 in 4 steps of 64.
__global__ __launch_bounds__(512) void expert_hv_kernel(
    const bf16* __restrict__ Hin, const bf16* __restrict__ valuesT,
    const int* __restrict__ counts, const int* __restrict__ offsets,
    const int* __restrict__ btok, float* __restrict__ yacc) {
    int e = blockIdx.z;
    int n = counts[e];
    int tile = blockIdx.x;
    if (tile * 128 >= n) return;
    int vc = blockIdx.y;
    int off = offsets[e];
    int tid = threadIdx.x, lane = tid & 63, w = tid >> 6;
    int lr = lane & 15, lg = lane >> 4;

    __shared__ __align__(16) bf16 Hs[128 * 64];    // 16 KB, swizzled
    __shared__ __align__(16) bf16 VTs[256 * 64];   // 32 KB, swizzled
    __shared__ int s_tok[128];

    if (tid < 128) {
        int idxr = tile * 128 + tid;
        int tok = (idxr < n) ? btok[off + idxr] : 0;
        s_tok[tid] = tok & (NTOK - 1);
    }
    // no barrier needed here: s_tok is only read after the loop's barriers

    f32x4 acc[16] = {};   // wave w: rows [16w,16w+16) x v-cols [0,256)
    const bf16* vbase = valuesT + (size_t)e * (DMODEL * ESZ) + (size_t)vc * 256 * ESZ;
    int r0 = tid >> 3;
    int c8 = (tid & 7) * 8;
    int tbase = tile * 128;

    #pragma unroll
    for (int hc = 0; hc < 4; ++hc) {
        int hcol = hc * 64 + c8;
        {   // stage Hs rows r0, r0+64 (zero-fill beyond n)
            uint4 z = {0, 0, 0, 0};
            uint4 v0 = (tbase + r0 < n)
                ? *(const uint4*)(Hin + (size_t)(off + tbase + r0) * ESZ + hcol) : z;
            *(uint4*)&Hs[sw(r0, c8)] = v0;
            uint4 v1 = (tbase + r0 + 64 < n)
                ? *(const uint4*)(Hin + (size_t)(off + tbase + r0 + 64) * ESZ + hcol) : z;
            *(uint4*)&Hs[sw(r0 + 64, c8)] = v1;
        }
        #pragma unroll
        for (int i = 0; i < 4; ++i) {   // stage VTs [256 v][64 h]
            int vr = r0 + 64 * i;
            *(uint4*)&VTs[sw(vr, c8)] = *(const uint4*)(vbase + (size_t)vr * ESZ + hcol);
        }
        __syncthreads();
        #pragma unroll
        for (int ks = 0; ks < 2; ++ks) {
            bf16x8 a = *(bf16x8*)&Hs[sw(w * 16 + lr, ks * 32 + lg * 8)];
            #pragma unroll
            for (int ct = 0; ct < 16; ++ct) {
                bf16x8 b = *(bf16x8*)&VTs[sw(ct * 16 + lr, ks * 32 + lg * 8)];
                acc[ct] = __builtin_amdgcn_mfma_f32_16x16x32_bf16(a, b, acc[ct], 0, 0, 0);
            }
        }
        __syncthreads();
    }

    int rbase = w * 16 + lg * 4;
    #pragma unroll
    for (int r = 0; r < 4; ++r) {
        int row = rbase + r;
        if (tbase + row < n) {
            float* yp = yacc + (size_t)s_tok[row] * DMODEL + vc * 256;
            #pragma unroll
            for (int ct = 0; ct < 16; ++ct)
                unsafeAtomicAdd(yp + ct * 16 + lr, acc[ct][r]);
        }
    }
}

// ---------------- f32 accumulator -> f32 out (NaN-scrubbed) ----------------
__global__ void finalize_kernel(const float* __restrict__ yacc, float* __restrict__ out) {
    size_t i = ((size_t)blockIdx.x * 256 + threadIdx.x) * 8;
    float4 a = *(const float4*)(yacc + i);
    float4 b = *(const float4*)(yacc + i + 4);
    float v[8] = {a.x, a.y, a.z, a.w, b.x, b.y, b.z, b.w};
    #pragma unroll
    for (int j = 0; j < 8; ++j) v[j] = (v[j] == v[j]) ? v[j] : 0.f;
    *(float4*)(out + i)     = make_float4(v[0], v[1], v[2], v[3]);
    *(float4*)(out + i + 4) = make_float4(v[4], v[5], v[6], v[7]);
}

extern "C" void kernel_launch(void* const* d_in, const int* in_sizes, int n_in,
                              void* d_out, int out_size, void* d_ws, size_t ws_size,
                              hipStream_t stream) {
    const float* x      = (const float*)d_in[0];
    const float* keys   = (const float*)d_in[1];
    const float* values = (const float*)d_in[2];
    const float* esel   = (const float*)d_in[3];
    float* out = (float*)d_out;   // [8192][1024] f32 = 32 MiB

    // Workspace map — total exactly 51380224 B (proven-safe bound from round 3):
    uint8_t* ws = (uint8_t*)d_ws;
    int*   eidx     = (int*)(ws);                        // 131072 B
    float* egate    = (float*)(ws + 131072);             // 131072 B
    int*   btok     = (int*)(ws + 262144);               // 131072 B
    float* bgate    = (float*)(ws + 393216);             // 131072 B
    int*   counts   = (int*)(ws + 524288);               // [32]
    int*   offsets  = (int*)(ws + 524416);               // [32]
    int*   counts_q = (int*)(ws + 524544);               // [32][4]
    bf16*  keysT    = (bf16*)(ws + 1048576);             // 16 MiB
    float* yacc     = (float*)(ws + 17825792);           // 32 MiB
    // d_out (32 MiB) as scratch until finalize: VT in first half, H in second.
    bf16*  valuesT  = (bf16*)d_out;                      // 16 MiB: [32][1024][256]
    bf16*  Hbuf     = (bf16*)((uint8_t*)d_out + 16777216); // 16 MiB: [32768][256]

    hipMemsetAsync(yacc, 0, (size_t)NTOK * DMODEL * sizeof(float), stream);

    transpose_conv_kernel<<<dim3(16, 4, 32), 256, 0, stream>>>(values, valuesT, ESZ, DMODEL);
    transpose_conv_kernel<<<dim3(4, 16, 32), 256, 0, stream>>>(keys, keysT, DMODEL, ESZ);
    sel_kernel<<<NTOK / 4, 256, 0, stream>>>(x, esel, eidx, egate);
    hist_kernel<<<NEXP, 256, 0, stream>>>(eidx, counts, counts_q);
    scan_kernel<<<1, 64, 0, stream>>>(counts, offsets);
    compact_kernel<<<dim3(NEXP, 4), 64, 0, stream>>>(eidx, egate, offsets, counts_q, btok, bgate);
    expert_xk_kernel<<<dim3(64, NEXP), 512, 0, stream>>>(x, keysT, counts, offsets,
                                                         btok, bgate, Hbuf);
    expert_hv_kernel<<<dim3(64, 4, NEXP), 512, 0, stream>>>(Hbuf, valuesT, counts, offsets,
                                                            btok, yacc);
    finalize_kernel<<<(NTOK * DMODEL) / 2048, 256, 0, stream>>>(yacc, out);
}